// Round 1
// baseline (3202.265 us; speedup 1.0000x reference)
//
#include <hip/hip_runtime.h>
#include <hip/hip_bf16.h>
#include <math.h>

// ---------------------------------------------------------------------------
// Transformer block, fp32 correctness-first baseline.
// B=4, N=1024, C=1024, H=16, Dh=64, hidden=4096.
// Pipeline:
//   h  = LN1(x)
//   qkv = h @ qkv_w^T                      [4096 x 3072]
//   o  = attention(qkv)                    [4096 x 1024]
//   out = x + o @ proj_w^T + proj_b        (residual stream in d_out)
//   h2 = LN2(out)
//   u  = gelu(h2 @ fc1_w^T + fc1_b)        [4096 x 4096]
//   u  = LNh(u)   (in place)
//   out = out + u @ fc2_w^T + fc2_b
// Workspace layout (floats): h[4M] | qkv/u[16M] | o[4M]  = 96 MB
// ---------------------------------------------------------------------------

#define TOKENS 4096
#define CDIM   1024
#define HEADS  16
#define DHEAD  64
#define HID    4096

// ---------------- LayerNorm ----------------
__global__ __launch_bounds__(256) void ln_kernel(
    const float* __restrict__ x, const float* __restrict__ g,
    const float* __restrict__ b, float* __restrict__ y, int C)
{
    int row = blockIdx.x;
    const float* xr = x + (long)row * C;
    float* yr = y + (long)row * C;

    float s = 0.f, ss = 0.f;
    for (int i = threadIdx.x; i < C; i += 256) {
        float v = xr[i];
        s += v; ss += v * v;
    }
    // wave reduce (width 64)
    #pragma unroll
    for (int d = 32; d; d >>= 1) {
        s  += __shfl_down(s, d);
        ss += __shfl_down(ss, d);
    }
    __shared__ float buf[4][2];
    int wid = threadIdx.x >> 6, lane = threadIdx.x & 63;
    if (lane == 0) { buf[wid][0] = s; buf[wid][1] = ss; }
    __syncthreads();
    if (threadIdx.x == 0) {
        s = buf[0][0] + buf[1][0] + buf[2][0] + buf[3][0];
        ss = buf[0][1] + buf[1][1] + buf[2][1] + buf[3][1];
        buf[0][0] = s; buf[0][1] = ss;
    }
    __syncthreads();
    s = buf[0][0]; ss = buf[0][1];

    float invC = 1.f / (float)C;
    float mu = s * invC;
    float var = ss * invC - mu * mu;
    float inv = rsqrtf(var + 1e-5f);
    for (int i = threadIdx.x; i < C; i += 256) {
        yr[i] = (xr[i] - mu) * inv * g[i] + b[i];
    }
}

// ---------------- Tiled SGEMM: C = A[M,K] @ B[N,K]^T (+bias)(+gelu)(+residual)
#define BM 64
#define BN 64
#define BK 16
__global__ __launch_bounds__(256) void gemm_bt(
    const float* __restrict__ A, const float* __restrict__ B,
    const float* __restrict__ bias, const float* __restrict__ residual,
    float* __restrict__ C, int M, int N, int K, int act)
{
    __shared__ float As[BK][BM + 1];
    __shared__ float Bs[BK][BN + 1];
    int tid = threadIdx.x;
    int bm = blockIdx.y * BM;
    int bn = blockIdx.x * BN;
    int tr = tid >> 4;   // 0..15
    int tc = tid & 15;   // 0..15
    int lk = tid & 15;   // k index within tile
    int lm = tid >> 4;   // row base within tile, step 16

    float acc[4][4] = {};

    for (int k0 = 0; k0 < K; k0 += BK) {
        #pragma unroll
        for (int i = 0; i < 4; ++i) {
            As[lk][lm + 16 * i] = A[(long)(bm + lm + 16 * i) * K + k0 + lk];
            Bs[lk][lm + 16 * i] = B[(long)(bn + lm + 16 * i) * K + k0 + lk];
        }
        __syncthreads();
        #pragma unroll
        for (int k = 0; k < BK; ++k) {
            float a[4], b4[4];
            #pragma unroll
            for (int i = 0; i < 4; ++i) a[i] = As[k][tr * 4 + i];
            #pragma unroll
            for (int j = 0; j < 4; ++j) b4[j] = Bs[k][tc * 4 + j];
            #pragma unroll
            for (int i = 0; i < 4; ++i)
                #pragma unroll
                for (int j = 0; j < 4; ++j)
                    acc[i][j] += a[i] * b4[j];
        }
        __syncthreads();
    }

    #pragma unroll
    for (int i = 0; i < 4; ++i) {
        int row = bm + tr * 4 + i;
        #pragma unroll
        for (int j = 0; j < 4; ++j) {
            int col = bn + tc * 4 + j;
            float v = acc[i][j];
            if (bias) v += bias[col];
            if (act == 1) v = 0.5f * v * (1.f + erff(v * 0.70710678118654752f));
            if (residual) v += residual[(long)row * N + col];
            C[(long)row * N + col] = v;
        }
    }
}

// ---------------- Flash-style attention ----------------
// qkv: [4096, 3072] where col = which*1024 + h*64 + d
// One thread owns one query row. Block = 256 threads = 256 queries of one (b,h).
// Grid = 64 (b,h) * 4 query-blocks = 256 blocks.
__global__ __launch_bounds__(256) void attn_kernel(
    const float* __restrict__ qkv, float* __restrict__ o_out)
{
    const int C3 = 3 * CDIM;
    int bh = blockIdx.x >> 2;
    int qb = blockIdx.x & 3;
    int b = bh >> 4, hh = bh & 15;
    int tid = threadIdx.x;
    int n = qb * 256 + tid;

    // load this thread's query row (64 contiguous floats)
    float q[DHEAD];
    {
        const float4* qp = (const float4*)(qkv + (long)(b * 1024 + n) * C3 + hh * DHEAD);
        #pragma unroll
        for (int i = 0; i < 16; ++i) {
            float4 t = qp[i];
            q[4 * i] = t.x; q[4 * i + 1] = t.y; q[4 * i + 2] = t.z; q[4 * i + 3] = t.w;
        }
    }

    float oacc[DHEAD] = {};
    float m = -1e30f, l = 0.f;

    __shared__ float Ks[64][DHEAD];
    __shared__ float Vs[64][DHEAD];

    #pragma unroll 1
    for (int kt = 0; kt < 16; ++kt) {
        __syncthreads();
        // cooperative load of 64 keys + 64 values (4096 floats each)
        {
            long base = (long)(b * 1024 + kt * 64) * C3 + hh * DHEAD;
            const float* Kg = qkv + base + 1024;
            const float* Vg = qkv + base + 2048;
            #pragma unroll
            for (int i = 0; i < 4; ++i) {
                int f = tid + 256 * i;           // float4 index
                int key = f >> 4, d4 = f & 15;
                float4 kv = *(const float4*)(Kg + (long)key * C3 + d4 * 4);
                float4 vv = *(const float4*)(Vg + (long)key * C3 + d4 * 4);
                *(float4*)&Ks[key][d4 * 4] = kv;
                *(float4*)&Vs[key][d4 * 4] = vv;
            }
        }
        __syncthreads();

        // process tile in chunks of 16 keys (keeps code size / regs bounded)
        #pragma unroll 1
        for (int c = 0; c < 4; ++c) {
            float s16[16];
            #pragma unroll
            for (int kk = 0; kk < 16; ++kk) {
                int key = c * 16 + kk;
                float acc = 0.f;
                #pragma unroll
                for (int d = 0; d < DHEAD; ++d) acc += q[d] * Ks[key][d];
                s16[kk] = acc * 0.125f;   // Dh^-0.5
            }
            float tm = s16[0];
            #pragma unroll
            for (int kk = 1; kk < 16; ++kk) tm = fmaxf(tm, s16[kk]);
            float mn = fmaxf(m, tm);
            float alpha = __expf(m - mn);
            l *= alpha;
            #pragma unroll
            for (int d = 0; d < DHEAD; ++d) oacc[d] *= alpha;
            #pragma unroll
            for (int kk = 0; kk < 16; ++kk) {
                int key = c * 16 + kk;
                float p = __expf(s16[kk] - mn);
                l += p;
                #pragma unroll
                for (int d = 0; d < DHEAD; ++d) oacc[d] += p * Vs[key][d];
            }
            m = mn;
        }
    }

    float invl = 1.f / l;
    float4* op = (float4*)(o_out + (long)(b * 1024 + n) * CDIM + hh * DHEAD);
    #pragma unroll
    for (int i = 0; i < 16; ++i) {
        float4 t;
        t.x = oacc[4 * i] * invl;
        t.y = oacc[4 * i + 1] * invl;
        t.z = oacc[4 * i + 2] * invl;
        t.w = oacc[4 * i + 3] * invl;
        op[i] = t;
    }
}

// ---------------------------------------------------------------------------
extern "C" void kernel_launch(void* const* d_in, const int* in_sizes, int n_in,
                              void* d_out, int out_size, void* d_ws, size_t ws_size,
                              hipStream_t stream)
{
    const float* x      = (const float*)d_in[0];
    const float* qkv_w  = (const float*)d_in[1];
    const float* proj_w = (const float*)d_in[2];
    const float* proj_b = (const float*)d_in[3];
    const float* fc1_w  = (const float*)d_in[4];
    const float* fc1_b  = (const float*)d_in[5];
    const float* fc2_w  = (const float*)d_in[6];
    const float* fc2_b  = (const float*)d_in[7];
    const float* ln1_g  = (const float*)d_in[8];
    const float* ln1_b  = (const float*)d_in[9];
    const float* ln2_g  = (const float*)d_in[10];
    const float* ln2_b  = (const float*)d_in[11];
    const float* lnh_g  = (const float*)d_in[12];
    const float* lnh_b  = (const float*)d_in[13];

    float* out = (float*)d_out;
    float* ws  = (float*)d_ws;

    // workspace layout (floats)
    float* h   = ws;                        //  4M floats (16 MB)  h / h2
    float* qkv = ws + 4l * 1024 * 1024;     // 12M floats (48 MB)
    float* u   = qkv;                       // 16M floats (64 MB), reuses qkv region
    float* o   = ws + 20l * 1024 * 1024;    //  4M floats (16 MB)

    // 1. h = LN1(x)
    ln_kernel<<<TOKENS, 256, 0, stream>>>(x, ln1_g, ln1_b, h, CDIM);
    // 2. qkv = h @ qkv_w^T
    gemm_bt<<<dim3(3072 / BN, TOKENS / BM), 256, 0, stream>>>(
        h, qkv_w, nullptr, nullptr, qkv, TOKENS, 3072, CDIM, 0);
    // 3. o = attention(qkv)
    attn_kernel<<<256, 256, 0, stream>>>(qkv, o);
    // 4. out = x + o @ proj_w^T + proj_b
    gemm_bt<<<dim3(CDIM / BN, TOKENS / BM), 256, 0, stream>>>(
        o, proj_w, proj_b, x, out, TOKENS, CDIM, CDIM, 0);
    // 5. h2 = LN2(out)
    ln_kernel<<<TOKENS, 256, 0, stream>>>(out, ln2_g, ln2_b, h, CDIM);
    // 6. u = gelu(h2 @ fc1_w^T + fc1_b)
    gemm_bt<<<dim3(HID / BN, TOKENS / BM), 256, 0, stream>>>(
        h, fc1_w, fc1_b, nullptr, u, TOKENS, HID, CDIM, 1);
    // 7. u = LNh(u) in place
    ln_kernel<<<TOKENS, 256, 0, stream>>>(u, lnh_g, lnh_b, u, HID);
    // 8. out = out + u @ fc2_w^T + fc2_b
    gemm_bt<<<dim3(CDIM / BN, TOKENS / BM), 256, 0, stream>>>(
        u, fc2_w, fc2_b, out, out, TOKENS, CDIM, HID, 0);
}

// Round 2
// 1406.261 us; speedup vs baseline: 2.2771x; 2.2771x over previous
//
#include <hip/hip_runtime.h>
#include <hip/hip_bf16.h>
#include <math.h>

// ---------------------------------------------------------------------------
// Transformer block. R1: all four GEMMs moved to bf16 MFMA (m97 structure:
// 128x128 tile, BK=32, mfma_f32_16x16x32_bf16, global_load_lds width=16).
// Activations flow as bf16; residual stream stays fp32 in d_out.
//   h  = LN1(x)              (f32 -> bf16)
//   qkv = h @ qkv_w^T        (bf16 mfma -> bf16)
//   o  = attention(qkv)      (bf16 in, fp32 compute, bf16 out)
//   out = x + o @ proj_w^T + proj_b          (f32 out)
//   h2 = LN2(out)            (f32 -> bf16)
//   u  = gelu(h2 @ fc1_w^T + fc1_b)          (bf16 out)
//   u  = LNh(u) in place     (bf16 -> bf16)
//   out = out + u @ fc2_w^T + fc2_b          (f32 out)
// Workspace (96 MB): wbf16[24] | h[8] | qkv[24] | o[8] | u[32]
// ---------------------------------------------------------------------------

#define TOKENS 4096
#define CDIM   1024
#define HEADS  16
#define DHEAD  64
#define HID    4096

typedef __attribute__((ext_vector_type(4))) float  floatx4;
typedef __attribute__((ext_vector_type(8))) short  short8;  // 8 x bf16 frag

// ---------------- fp32 -> bf16 convert (weights) ----------------
__global__ __launch_bounds__(256) void cvt_kernel(
    const float* __restrict__ in, __hip_bfloat16* __restrict__ out, int n4)
{
    int i = blockIdx.x * 256 + threadIdx.x;
    if (i < n4) {
        float4 v = ((const float4*)in)[i];
        __hip_bfloat16 t[4];
        t[0] = __float2bfloat16(v.x);
        t[1] = __float2bfloat16(v.y);
        t[2] = __float2bfloat16(v.z);
        t[3] = __float2bfloat16(v.w);
        *(uint2*)(out + 4l * i) = *(uint2*)t;
    }
}

// ---------------- LayerNorm: fp32 in -> bf16 out ----------------
__global__ __launch_bounds__(256) void ln_f32_kernel(
    const float* __restrict__ x, const float* __restrict__ g,
    const float* __restrict__ b, __hip_bfloat16* __restrict__ y, int C)
{
    int row = blockIdx.x;
    const float* xr = x + (long)row * C;
    __hip_bfloat16* yr = y + (long)row * C;

    float s = 0.f, ss = 0.f;
    for (int i = threadIdx.x; i < C; i += 256) {
        float v = xr[i];
        s += v; ss += v * v;
    }
    #pragma unroll
    for (int d = 32; d; d >>= 1) {
        s  += __shfl_down(s, d);
        ss += __shfl_down(ss, d);
    }
    __shared__ float buf[4][2];
    int wid = threadIdx.x >> 6, lane = threadIdx.x & 63;
    if (lane == 0) { buf[wid][0] = s; buf[wid][1] = ss; }
    __syncthreads();
    if (threadIdx.x == 0) {
        s = buf[0][0] + buf[1][0] + buf[2][0] + buf[3][0];
        ss = buf[0][1] + buf[1][1] + buf[2][1] + buf[3][1];
        buf[0][0] = s; buf[0][1] = ss;
    }
    __syncthreads();
    s = buf[0][0]; ss = buf[0][1];

    float invC = 1.f / (float)C;
    float mu = s * invC;
    float var = ss * invC - mu * mu;
    float inv = rsqrtf(var + 1e-5f);
    for (int i = threadIdx.x; i < C; i += 256) {
        yr[i] = __float2bfloat16((xr[i] - mu) * inv * g[i] + b[i]);
    }
}

// ---------------- LayerNorm: bf16 in -> bf16 out (in place ok) ----------------
__global__ __launch_bounds__(256) void ln_bf16_kernel(
    const __hip_bfloat16* __restrict__ x, const float* __restrict__ g,
    const float* __restrict__ b, __hip_bfloat16* __restrict__ y, int C)
{
    int row = blockIdx.x;
    const __hip_bfloat16* xr = x + (long)row * C;
    __hip_bfloat16* yr = y + (long)row * C;

    float s = 0.f, ss = 0.f;
    for (int i = threadIdx.x; i < C; i += 256) {
        float v = __bfloat162float(xr[i]);
        s += v; ss += v * v;
    }
    #pragma unroll
    for (int d = 32; d; d >>= 1) {
        s  += __shfl_down(s, d);
        ss += __shfl_down(ss, d);
    }
    __shared__ float buf[4][2];
    int wid = threadIdx.x >> 6, lane = threadIdx.x & 63;
    if (lane == 0) { buf[wid][0] = s; buf[wid][1] = ss; }
    __syncthreads();
    if (threadIdx.x == 0) {
        s = buf[0][0] + buf[1][0] + buf[2][0] + buf[3][0];
        ss = buf[0][1] + buf[1][1] + buf[2][1] + buf[3][1];
        buf[0][0] = s; buf[0][1] = ss;
    }
    __syncthreads();
    s = buf[0][0]; ss = buf[0][1];

    float invC = 1.f / (float)C;
    float mu = s * invC;
    float var = ss * invC - mu * mu;
    float inv = rsqrtf(var + 1e-5f);
    for (int i = threadIdx.x; i < C; i += 256) {
        float v = __bfloat162float(xr[i]);
        yr[i] = __float2bfloat16((v - mu) * inv * g[i] + b[i]);
    }
}

// ---------------- async 16B global->LDS ----------------
__device__ __forceinline__ void gld_lds16(const void* gp, void* lp)
{
    __builtin_amdgcn_global_load_lds(
        (__attribute__((address_space(1))) void*)(gp),
        (__attribute__((address_space(3))) void*)(lp),
        16, 0, 0);
}

// ---------------- bf16 MFMA GEMM: C = A[M,K] @ W[N,K]^T (+bias)(+gelu)(+res)
// 128x128 tile, BK=32, 256 threads = 4 waves in 2x2, each wave 4x4 16x16 tiles.
#define GBM 128
#define GBN 128
#define GBK 32
__global__ __launch_bounds__(256) void gemm_mfma(
    const __hip_bfloat16* __restrict__ A,
    const __hip_bfloat16* __restrict__ W,
    const float* __restrict__ bias, const float* __restrict__ residual,
    void* __restrict__ Cout, int M, int N, int K, int act, int out_bf16)
{
    __shared__ __hip_bfloat16 Asl[GBM * GBK];  // 8 KB, row-major [128][32]
    __shared__ __hip_bfloat16 Bsl[GBN * GBK];  // 8 KB

    int tid = threadIdx.x;
    int wave = tid >> 6, lane = tid & 63;
    int bm = blockIdx.y * GBM, bn = blockIdx.x * GBN;
    int wr = wave & 1, wc = wave >> 1;
    int fm = lane & 15;      // row (A) / col (B) within 16
    int quad = lane >> 4;    // k sub-block: k = quad*8 + j

    floatx4 acc[4][4] = {};

    // staging addressing: chunk cc = wave*2+c covers LDS bytes [cc*1024, +1024)
    // lane -> row = cc*16 + lane/4, k = (lane&3)*8
    int srow = (lane >> 2);
    int skk  = (lane & 3) * 8;

    for (int k0 = 0; k0 < K; k0 += GBK) {
        #pragma unroll
        for (int c = 0; c < 2; ++c) {
            int cc = wave * 2 + c;
            int row = cc * 16 + srow;
            gld_lds16(A + (long)(bm + row) * K + k0 + skk, Asl + cc * 512);
            gld_lds16(W + (long)(bn + row) * K + k0 + skk, Bsl + cc * 512);
        }
        __syncthreads();

        short8 af[4], bfr[4];
        #pragma unroll
        for (int i = 0; i < 4; ++i)
            af[i] = *(const short8*)(Asl + (wr * 64 + i * 16 + fm) * GBK + quad * 8);
        #pragma unroll
        for (int j = 0; j < 4; ++j)
            bfr[j] = *(const short8*)(Bsl + (wc * 64 + j * 16 + fm) * GBK + quad * 8);
        #pragma unroll
        for (int i = 0; i < 4; ++i)
            #pragma unroll
            for (int j = 0; j < 4; ++j)
                acc[i][j] = __builtin_amdgcn_mfma_f32_16x16x32_bf16(
                    af[i], bfr[j], acc[i][j], 0, 0, 0);
        __syncthreads();
    }

    // epilogue: C/D layout (16x16): col = lane&15, row = quad*4 + reg
    int mbase = bm + wr * 64;
    int nbase = bn + wc * 64;
    #pragma unroll
    for (int i = 0; i < 4; ++i) {
        #pragma unroll
        for (int j = 0; j < 4; ++j) {
            int ncol = nbase + j * 16 + fm;
            #pragma unroll
            for (int r = 0; r < 4; ++r) {
                int mrow = mbase + i * 16 + quad * 4 + r;
                float v = acc[i][j][r];
                if (bias) v += bias[ncol];
                if (act == 1) v = 0.5f * v * (1.f + erff(v * 0.70710678118654752f));
                if (residual) v += residual[(long)mrow * N + ncol];
                if (out_bf16)
                    ((__hip_bfloat16*)Cout)[(long)mrow * N + ncol] = __float2bfloat16(v);
                else
                    ((float*)Cout)[(long)mrow * N + ncol] = v;
            }
        }
    }
}

// ---------------- Flash-style attention (bf16 in/out, fp32 compute) ----------
__global__ __launch_bounds__(256) void attn_kernel(
    const __hip_bfloat16* __restrict__ qkv, __hip_bfloat16* __restrict__ o_out)
{
    const int C3 = 3 * CDIM;
    int bh = blockIdx.x >> 2;
    int qb = blockIdx.x & 3;
    int b = bh >> 4, hh = bh & 15;
    int tid = threadIdx.x;
    int n = qb * 256 + tid;

    float q[DHEAD];
    {
        const uint4* qp = (const uint4*)(qkv + (long)(b * 1024 + n) * C3 + hh * DHEAD);
        #pragma unroll
        for (int i = 0; i < 8; ++i) {
            uint4 t = qp[i];
            const __hip_bfloat16* ph = (const __hip_bfloat16*)&t;
            #pragma unroll
            for (int j = 0; j < 8; ++j) q[8 * i + j] = __bfloat162float(ph[j]);
        }
    }

    float oacc[DHEAD] = {};
    float m = -1e30f, l = 0.f;

    __shared__ float Ks[64][DHEAD];
    __shared__ float Vs[64][DHEAD];

    #pragma unroll 1
    for (int kt = 0; kt < 16; ++kt) {
        __syncthreads();
        {
            long base = (long)(b * 1024 + kt * 64) * C3 + hh * DHEAD;
            const __hip_bfloat16* Kg = qkv + base + 1024;
            const __hip_bfloat16* Vg = qkv + base + 2048;
            #pragma unroll
            for (int i = 0; i < 2; ++i) {
                int f = tid + 256 * i;          // 16B chunk index (8 bf16)
                int key = f >> 3, d8 = (f & 7) * 8;
                uint4 kv = *(const uint4*)(Kg + (long)key * C3 + d8);
                uint4 vv = *(const uint4*)(Vg + (long)key * C3 + d8);
                const __hip_bfloat16* pk = (const __hip_bfloat16*)&kv;
                const __hip_bfloat16* pv = (const __hip_bfloat16*)&vv;
                #pragma unroll
                for (int j = 0; j < 8; ++j) {
                    Ks[key][d8 + j] = __bfloat162float(pk[j]);
                    Vs[key][d8 + j] = __bfloat162float(pv[j]);
                }
            }
        }
        __syncthreads();

        #pragma unroll 1
        for (int c = 0; c < 4; ++c) {
            float s16[16];
            #pragma unroll
            for (int kk = 0; kk < 16; ++kk) {
                int key = c * 16 + kk;
                float acc = 0.f;
                #pragma unroll
                for (int d = 0; d < DHEAD; ++d) acc += q[d] * Ks[key][d];
                s16[kk] = acc * 0.125f;
            }
            float tm = s16[0];
            #pragma unroll
            for (int kk = 1; kk < 16; ++kk) tm = fmaxf(tm, s16[kk]);
            float mn = fmaxf(m, tm);
            float alpha = __expf(m - mn);
            l *= alpha;
            #pragma unroll
            for (int d = 0; d < DHEAD; ++d) oacc[d] *= alpha;
            #pragma unroll
            for (int kk = 0; kk < 16; ++kk) {
                int key = c * 16 + kk;
                float p = __expf(s16[kk] - mn);
                l += p;
                #pragma unroll
                for (int d = 0; d < DHEAD; ++d) oacc[d] += p * Vs[key][d];
            }
            m = mn;
        }
    }

    float invl = 1.f / l;
    __hip_bfloat16* op = o_out + (long)(b * 1024 + n) * CDIM + hh * DHEAD;
    #pragma unroll
    for (int i = 0; i < 8; ++i) {
        __hip_bfloat16 t[8];
        #pragma unroll
        for (int j = 0; j < 8; ++j) t[j] = __float2bfloat16(oacc[8 * i + j] * invl);
        *(uint4*)(op + 8 * i) = *(uint4*)t;
    }
}

// ---------------------------------------------------------------------------
extern "C" void kernel_launch(void* const* d_in, const int* in_sizes, int n_in,
                              void* d_out, int out_size, void* d_ws, size_t ws_size,
                              hipStream_t stream)
{
    const float* x      = (const float*)d_in[0];
    const float* qkv_w  = (const float*)d_in[1];
    const float* proj_w = (const float*)d_in[2];
    const float* proj_b = (const float*)d_in[3];
    const float* fc1_w  = (const float*)d_in[4];
    const float* fc1_b  = (const float*)d_in[5];
    const float* fc2_w  = (const float*)d_in[6];
    const float* fc2_b  = (const float*)d_in[7];
    const float* ln1_g  = (const float*)d_in[8];
    const float* ln1_b  = (const float*)d_in[9];
    const float* ln2_g  = (const float*)d_in[10];
    const float* ln2_b  = (const float*)d_in[11];
    const float* lnh_g  = (const float*)d_in[12];
    const float* lnh_b  = (const float*)d_in[13];

    float* out = (float*)d_out;

    // workspace layout (bf16 elements)
    __hip_bfloat16* wsb     = (__hip_bfloat16*)d_ws;
    __hip_bfloat16* qkvw_bf = wsb;                               //  3M ->  6 MB
    __hip_bfloat16* fc1w_bf = qkvw_bf + 3l * 1024 * 1024;        //  4M ->  8 MB
    __hip_bfloat16* fc2w_bf = fc1w_bf + 4l * 1024 * 1024;        //  4M ->  8 MB
    __hip_bfloat16* projw_bf= fc2w_bf + 4l * 1024 * 1024;        //  1M ->  2 MB
    __hip_bfloat16* h_bf    = projw_bf + 1l * 1024 * 1024;       //  4M ->  8 MB
    __hip_bfloat16* qkv_bf  = h_bf + 4l * 1024 * 1024;           // 12M -> 24 MB
    __hip_bfloat16* o_bf    = qkv_bf + 12l * 1024 * 1024;        //  4M ->  8 MB
    __hip_bfloat16* u_bf    = o_bf + 4l * 1024 * 1024;           // 16M -> 32 MB (=96)

    // 0. weights fp32 -> bf16
    cvt_kernel<<<(3 * 1024 * 1024 / 4 + 255) / 256, 256, 0, stream>>>(qkv_w, qkvw_bf, 3 * 1024 * 1024 / 4);
    cvt_kernel<<<(4 * 1024 * 1024 / 4 + 255) / 256, 256, 0, stream>>>(fc1_w, fc1w_bf, 4 * 1024 * 1024 / 4);
    cvt_kernel<<<(4 * 1024 * 1024 / 4 + 255) / 256, 256, 0, stream>>>(fc2_w, fc2w_bf, 4 * 1024 * 1024 / 4);
    cvt_kernel<<<(1024 * 1024 / 4 + 255) / 256, 256, 0, stream>>>(proj_w, projw_bf, 1024 * 1024 / 4);

    // 1. h = LN1(x)
    ln_f32_kernel<<<TOKENS, 256, 0, stream>>>(x, ln1_g, ln1_b, h_bf, CDIM);
    // 2. qkv = h @ qkv_w^T  (bf16 out)
    gemm_mfma<<<dim3(3072 / GBN, TOKENS / GBM), 256, 0, stream>>>(
        h_bf, qkvw_bf, nullptr, nullptr, qkv_bf, TOKENS, 3072, CDIM, 0, 1);
    // 3. o = attention(qkv)
    attn_kernel<<<256, 256, 0, stream>>>(qkv_bf, o_bf);
    // 4. out = x + o @ proj_w^T + proj_b  (f32 out)
    gemm_mfma<<<dim3(CDIM / GBN, TOKENS / GBM), 256, 0, stream>>>(
        o_bf, projw_bf, proj_b, x, out, TOKENS, CDIM, CDIM, 0, 0);
    // 5. h2 = LN2(out)
    ln_f32_kernel<<<TOKENS, 256, 0, stream>>>(out, ln2_g, ln2_b, h_bf, CDIM);
    // 6. u = gelu(h2 @ fc1_w^T + fc1_b)  (bf16 out)
    gemm_mfma<<<dim3(HID / GBN, TOKENS / GBM), 256, 0, stream>>>(
        h_bf, fc1w_bf, fc1_b, nullptr, u_bf, TOKENS, HID, CDIM, 1, 1);
    // 7. u = LNh(u) in place
    ln_bf16_kernel<<<TOKENS, 256, 0, stream>>>(u_bf, lnh_g, lnh_b, u_bf, HID);
    // 8. out = out + u @ fc2_w^T + fc2_b  (f32 out)
    gemm_mfma<<<dim3(CDIM / GBN, TOKENS / GBM), 256, 0, stream>>>(
        u_bf, fc2w_bf, fc2_b, out, out, TOKENS, CDIM, HID, 0, 0);
}

// Round 3
// 504.080 us; speedup vs baseline: 6.3527x; 2.7898x over previous
//
#include <hip/hip_runtime.h>
#include <hip/hip_bf16.h>
#include <math.h>

// ---------------------------------------------------------------------------
// Transformer block. R2: attention rewritten as MFMA flash kernel.
//   - S^T = K@Q^T per wave (16 queries), online softmax per-lane (1 query/lane)
//   - P round-trip through wave-private LDS (C-layout -> A-operand layout)
//   - V staged transposed (d-major) in LDS with XOR dword swizzle
// GEMMs: m97-style 128x128 bf16 MFMA (unchanged from R1).
// ---------------------------------------------------------------------------

#define TOKENS 4096
#define CDIM   1024
#define HEADS  16
#define DHEAD  64
#define HID    4096

typedef __attribute__((ext_vector_type(4))) float  floatx4;
typedef __attribute__((ext_vector_type(8))) short  short8;  // 8 x bf16 frag

// ---------------- fp32 -> bf16 convert (weights) ----------------
__global__ __launch_bounds__(256) void cvt_kernel(
    const float* __restrict__ in, __hip_bfloat16* __restrict__ out, int n4)
{
    int i = blockIdx.x * 256 + threadIdx.x;
    if (i < n4) {
        float4 v = ((const float4*)in)[i];
        __hip_bfloat16 t[4];
        t[0] = __float2bfloat16(v.x);
        t[1] = __float2bfloat16(v.y);
        t[2] = __float2bfloat16(v.z);
        t[3] = __float2bfloat16(v.w);
        *(uint2*)(out + 4l * i) = *(uint2*)t;
    }
}

// ---------------- LayerNorm: fp32 in -> bf16 out ----------------
__global__ __launch_bounds__(256) void ln_f32_kernel(
    const float* __restrict__ x, const float* __restrict__ g,
    const float* __restrict__ b, __hip_bfloat16* __restrict__ y, int C)
{
    int row = blockIdx.x;
    const float* xr = x + (long)row * C;
    __hip_bfloat16* yr = y + (long)row * C;

    float s = 0.f, ss = 0.f;
    for (int i = threadIdx.x; i < C; i += 256) {
        float v = xr[i];
        s += v; ss += v * v;
    }
    #pragma unroll
    for (int d = 32; d; d >>= 1) {
        s  += __shfl_down(s, d);
        ss += __shfl_down(ss, d);
    }
    __shared__ float buf[4][2];
    int wid = threadIdx.x >> 6, lane = threadIdx.x & 63;
    if (lane == 0) { buf[wid][0] = s; buf[wid][1] = ss; }
    __syncthreads();
    if (threadIdx.x == 0) {
        s = buf[0][0] + buf[1][0] + buf[2][0] + buf[3][0];
        ss = buf[0][1] + buf[1][1] + buf[2][1] + buf[3][1];
        buf[0][0] = s; buf[0][1] = ss;
    }
    __syncthreads();
    s = buf[0][0]; ss = buf[0][1];

    float invC = 1.f / (float)C;
    float mu = s * invC;
    float var = ss * invC - mu * mu;
    float inv = rsqrtf(var + 1e-5f);
    for (int i = threadIdx.x; i < C; i += 256) {
        yr[i] = __float2bfloat16((xr[i] - mu) * inv * g[i] + b[i]);
    }
}

// ---------------- LayerNorm: bf16 in -> bf16 out (in place ok) ----------------
__global__ __launch_bounds__(256) void ln_bf16_kernel(
    const __hip_bfloat16* __restrict__ x, const float* __restrict__ g,
    const float* __restrict__ b, __hip_bfloat16* __restrict__ y, int C)
{
    int row = blockIdx.x;
    const __hip_bfloat16* xr = x + (long)row * C;
    __hip_bfloat16* yr = y + (long)row * C;

    float s = 0.f, ss = 0.f;
    for (int i = threadIdx.x; i < C; i += 256) {
        float v = __bfloat162float(xr[i]);
        s += v; ss += v * v;
    }
    #pragma unroll
    for (int d = 32; d; d >>= 1) {
        s  += __shfl_down(s, d);
        ss += __shfl_down(ss, d);
    }
    __shared__ float buf[4][2];
    int wid = threadIdx.x >> 6, lane = threadIdx.x & 63;
    if (lane == 0) { buf[wid][0] = s; buf[wid][1] = ss; }
    __syncthreads();
    if (threadIdx.x == 0) {
        s = buf[0][0] + buf[1][0] + buf[2][0] + buf[3][0];
        ss = buf[0][1] + buf[1][1] + buf[2][1] + buf[3][1];
        buf[0][0] = s; buf[0][1] = ss;
    }
    __syncthreads();
    s = buf[0][0]; ss = buf[0][1];

    float invC = 1.f / (float)C;
    float mu = s * invC;
    float var = ss * invC - mu * mu;
    float inv = rsqrtf(var + 1e-5f);
    for (int i = threadIdx.x; i < C; i += 256) {
        float v = __bfloat162float(xr[i]);
        yr[i] = __float2bfloat16((v - mu) * inv * g[i] + b[i]);
    }
}

// ---------------- async 16B global->LDS ----------------
__device__ __forceinline__ void gld_lds16(const void* gp, void* lp)
{
    __builtin_amdgcn_global_load_lds(
        (__attribute__((address_space(1))) void*)(gp),
        (__attribute__((address_space(3))) void*)(lp),
        16, 0, 0);
}

// ---------------- bf16 MFMA GEMM (m97 structure, unchanged) ----------------
#define GBM 128
#define GBN 128
#define GBK 32
__global__ __launch_bounds__(256) void gemm_mfma(
    const __hip_bfloat16* __restrict__ A,
    const __hip_bfloat16* __restrict__ W,
    const float* __restrict__ bias, const float* __restrict__ residual,
    void* __restrict__ Cout, int M, int N, int K, int act, int out_bf16)
{
    __shared__ __hip_bfloat16 Asl[GBM * GBK];
    __shared__ __hip_bfloat16 Bsl[GBN * GBK];

    int tid = threadIdx.x;
    int wave = tid >> 6, lane = tid & 63;
    int bm = blockIdx.y * GBM, bn = blockIdx.x * GBN;
    int wr = wave & 1, wc = wave >> 1;
    int fm = lane & 15;
    int quad = lane >> 4;

    floatx4 acc[4][4] = {};

    int srow = (lane >> 2);
    int skk  = (lane & 3) * 8;

    for (int k0 = 0; k0 < K; k0 += GBK) {
        #pragma unroll
        for (int c = 0; c < 2; ++c) {
            int cc = wave * 2 + c;
            int row = cc * 16 + srow;
            gld_lds16(A + (long)(bm + row) * K + k0 + skk, Asl + cc * 512);
            gld_lds16(W + (long)(bn + row) * K + k0 + skk, Bsl + cc * 512);
        }
        __syncthreads();

        short8 af[4], bfr[4];
        #pragma unroll
        for (int i = 0; i < 4; ++i)
            af[i] = *(const short8*)(Asl + (wr * 64 + i * 16 + fm) * GBK + quad * 8);
        #pragma unroll
        for (int j = 0; j < 4; ++j)
            bfr[j] = *(const short8*)(Bsl + (wc * 64 + j * 16 + fm) * GBK + quad * 8);
        #pragma unroll
        for (int i = 0; i < 4; ++i)
            #pragma unroll
            for (int j = 0; j < 4; ++j)
                acc[i][j] = __builtin_amdgcn_mfma_f32_16x16x32_bf16(
                    af[i], bfr[j], acc[i][j], 0, 0, 0);
        __syncthreads();
    }

    int mbase = bm + wr * 64;
    int nbase = bn + wc * 64;
    #pragma unroll
    for (int i = 0; i < 4; ++i) {
        #pragma unroll
        for (int j = 0; j < 4; ++j) {
            int ncol = nbase + j * 16 + fm;
            #pragma unroll
            for (int r = 0; r < 4; ++r) {
                int mrow = mbase + i * 16 + quad * 4 + r;
                float v = acc[i][j][r];
                if (bias) v += bias[ncol];
                if (act == 1) v = 0.5f * v * (1.f + erff(v * 0.70710678118654752f));
                if (residual) v += residual[(long)mrow * N + ncol];
                if (out_bf16)
                    ((__hip_bfloat16*)Cout)[(long)mrow * N + ncol] = __float2bfloat16(v);
                else
                    ((float*)Cout)[(long)mrow * N + ncol] = v;
            }
        }
    }
}

// ---------------- MFMA flash attention ----------------
// Workgroup: 64 queries of one (b,h); 4 waves x 16 queries.
// Grid: 64 bh * 16 q-tiles = 1024 blocks.
// Per 64-key tile: S^T = K@Q^T (A=K LDS, B=Q regs); per-lane online softmax
// (lane owns query lane&15); P -> wave-private LDS (b64 packed) -> A-frag;
// PV with V^T staged d-major + XOR-swizzled dword columns.
// LDS rows padded to 144 B; all frag reads verified 8 dwords/bank (optimal).
__global__ __launch_bounds__(256) void attn_mfma(
    const __hip_bfloat16* __restrict__ qkv, __hip_bfloat16* __restrict__ o_out)
{
    __shared__ __align__(16) char Ks[64 * 144];
    __shared__ __align__(16) char Vt[64 * 144];
    __shared__ __align__(16) char Ps[4 * 16 * 144];

    const int C3 = 3 * CDIM;
    int wg = blockIdx.x;
    int bh = wg >> 4, qt = wg & 15;
    int b = bh >> 4, hh = bh & 15;
    int tid = threadIdx.x, wave = tid >> 6, lane = tid & 63;
    int l = lane & 15, quad = lane >> 4;

    // Q B-fragments, held in registers for the whole kernel
    const __hip_bfloat16* qrow =
        qkv + (long)(b * 1024 + qt * 64 + wave * 16 + l) * C3 + hh * DHEAD;
    short8 qf0 = *(const short8*)(qrow + quad * 8);
    short8 qf1 = *(const short8*)(qrow + 32 + quad * 8);

    char* Psw = Ps + wave * (16 * 144);

    // staging roles: sc = 16B d-chunk, skl = row index 0..31
    int sc = tid & 7;
    int skl = tid >> 3;

    const __hip_bfloat16* Kbase = qkv + (long)(b * 1024) * C3 + CDIM + hh * DHEAD;
    const __hip_bfloat16* Vbase = qkv + (long)(b * 1024) * C3 + 2 * CDIM + hh * DHEAD;

    floatx4 facc[4] = {};
    float mrun = -1e30f, lrun = 0.f;

    #pragma unroll 1
    for (int kt = 0; kt < 16; ++kt) {
        __syncthreads();
        {
            // K tile: row-major [64][72 bf16]
            const __hip_bfloat16* Kg = Kbase + (long)(kt * 64) * C3;
            #pragma unroll
            for (int it = 0; it < 2; ++it) {
                int key = skl + 32 * it;
                uint4 kv = *(const uint4*)(Kg + (long)key * C3 + sc * 8);
                *(uint4*)(Ks + key * 144 + sc * 16) = kv;
            }
            // V tile transposed: Vt[d][key], dword column kp swizzled by d-octet
            const __hip_bfloat16* Vg = Vbase + (long)(kt * 64) * C3;
            uint4 v0 = *(const uint4*)(Vg + (long)(2 * skl) * C3 + sc * 8);
            uint4 v1 = *(const uint4*)(Vg + (long)(2 * skl + 1) * C3 + sc * 8);
            const ushort* e0 = (const ushort*)&v0;
            const ushort* e1 = (const ushort*)&v1;
            int kpp = skl ^ (sc << 2);
            #pragma unroll
            for (int j = 0; j < 8; ++j) {
                unsigned dw = (unsigned)e0[j] | ((unsigned)e1[j] << 16);
                int d = sc * 8 + j;
                *(unsigned*)(Vt + d * 144 + kpp * 4) = dw;
            }
        }
        __syncthreads();

        // S^T = K @ Q^T : st[kb] = keys kb*16+quad*4+reg (rows) x queries (cols)
        floatx4 st[4] = {};
        #pragma unroll
        for (int kb = 0; kb < 4; ++kb) {
            short8 k0 = *(const short8*)(Ks + (kb * 16 + l) * 144 + quad * 16);
            short8 k1 = *(const short8*)(Ks + (kb * 16 + l) * 144 + 64 + quad * 16);
            st[kb] = __builtin_amdgcn_mfma_f32_16x16x32_bf16(k0, qf0, st[kb], 0, 0, 0);
            st[kb] = __builtin_amdgcn_mfma_f32_16x16x32_bf16(k1, qf1, st[kb], 0, 0, 0);
        }

        // online softmax: this lane owns query l; its 16 values are keys
        // kb*16 + quad*4 + r (disjoint across quads)
        float p[16];
        float tm = -1e30f;
        #pragma unroll
        for (int kb = 0; kb < 4; ++kb)
            #pragma unroll
            for (int r = 0; r < 4; ++r) {
                float s = st[kb][r] * 0.125f;   // Dh^-0.5
                p[kb * 4 + r] = s;
                tm = fmaxf(tm, s);
            }
        tm = fmaxf(tm, __shfl_xor(tm, 16));
        tm = fmaxf(tm, __shfl_xor(tm, 32));
        float mn = fmaxf(mrun, tm);
        float alpha = __expf(mrun - mn);
        float psum = 0.f;
        #pragma unroll
        for (int i = 0; i < 16; ++i) { p[i] = __expf(p[i] - mn); psum += p[i]; }
        psum += __shfl_xor(psum, 16);
        psum += __shfl_xor(psum, 32);
        lrun = lrun * alpha + psum;
        mrun = mn;

        // P -> wave-private LDS: row = query l, 4 consecutive keys per b64
        #pragma unroll
        for (int kb = 0; kb < 4; ++kb) {
            __hip_bfloat16 t[4];
            #pragma unroll
            for (int r = 0; r < 4; ++r) t[r] = __float2bfloat16(p[kb * 4 + r]);
            *(uint2*)(Psw + l * 144 + kb * 32 + quad * 8) = *(const uint2*)t;
        }

        // rescale O accumulator (rows are queries quad*4+r)
        float a0 = __shfl(alpha, quad * 4 + 0);
        float a1 = __shfl(alpha, quad * 4 + 1);
        float a2 = __shfl(alpha, quad * 4 + 2);
        float a3 = __shfl(alpha, quad * 4 + 3);
        #pragma unroll
        for (int db = 0; db < 4; ++db) {
            facc[db][0] *= a0; facc[db][1] *= a1;
            facc[db][2] *= a2; facc[db][3] *= a3;
        }

        // PV: A = P (m=query), B = Vt (n=d), contraction over 64 keys
        short8 pf0 = *(const short8*)(Psw + l * 144 + quad * 16);
        short8 pf1 = *(const short8*)(Psw + l * 144 + 64 + quad * 16);
        #pragma unroll
        for (int db = 0; db < 4; ++db) {
            int d = db * 16 + l;
            int o3 = (d >> 3) & 7;
            short8 v0 = *(const short8*)(Vt + d * 144 + ((quad ^ o3) << 4));
            short8 v1 = *(const short8*)(Vt + d * 144 + (((4 + quad) ^ o3) << 4));
            facc[db] = __builtin_amdgcn_mfma_f32_16x16x32_bf16(pf0, v0, facc[db], 0, 0, 0);
            facc[db] = __builtin_amdgcn_mfma_f32_16x16x32_bf16(pf1, v1, facc[db], 0, 0, 0);
        }
    }

    // epilogue: O[q][d] = facc / l_sum(q)
    float il0 = 1.f / __shfl(lrun, quad * 4 + 0);
    float il1 = 1.f / __shfl(lrun, quad * 4 + 1);
    float il2 = 1.f / __shfl(lrun, quad * 4 + 2);
    float il3 = 1.f / __shfl(lrun, quad * 4 + 3);
    __hip_bfloat16* orow =
        o_out + (long)(b * 1024 + qt * 64 + wave * 16) * CDIM + hh * DHEAD;
    #pragma unroll
    for (int db = 0; db < 4; ++db) {
        int col = db * 16 + l;
        orow[(quad * 4 + 0) * CDIM + col] = __float2bfloat16(facc[db][0] * il0);
        orow[(quad * 4 + 1) * CDIM + col] = __float2bfloat16(facc[db][1] * il1);
        orow[(quad * 4 + 2) * CDIM + col] = __float2bfloat16(facc[db][2] * il2);
        orow[(quad * 4 + 3) * CDIM + col] = __float2bfloat16(facc[db][3] * il3);
    }
}

// ---------------------------------------------------------------------------
extern "C" void kernel_launch(void* const* d_in, const int* in_sizes, int n_in,
                              void* d_out, int out_size, void* d_ws, size_t ws_size,
                              hipStream_t stream)
{
    const float* x      = (const float*)d_in[0];
    const float* qkv_w  = (const float*)d_in[1];
    const float* proj_w = (const float*)d_in[2];
    const float* proj_b = (const float*)d_in[3];
    const float* fc1_w  = (const float*)d_in[4];
    const float* fc1_b  = (const float*)d_in[5];
    const float* fc2_w  = (const float*)d_in[6];
    const float* fc2_b  = (const float*)d_in[7];
    const float* ln1_g  = (const float*)d_in[8];
    const float* ln1_b  = (const float*)d_in[9];
    const float* ln2_g  = (const float*)d_in[10];
    const float* ln2_b  = (const float*)d_in[11];
    const float* lnh_g  = (const float*)d_in[12];
    const float* lnh_b  = (const float*)d_in[13];

    float* out = (float*)d_out;

    __hip_bfloat16* wsb     = (__hip_bfloat16*)d_ws;
    __hip_bfloat16* qkvw_bf = wsb;
    __hip_bfloat16* fc1w_bf = qkvw_bf + 3l * 1024 * 1024;
    __hip_bfloat16* fc2w_bf = fc1w_bf + 4l * 1024 * 1024;
    __hip_bfloat16* projw_bf= fc2w_bf + 4l * 1024 * 1024;
    __hip_bfloat16* h_bf    = projw_bf + 1l * 1024 * 1024;
    __hip_bfloat16* qkv_bf  = h_bf + 4l * 1024 * 1024;
    __hip_bfloat16* o_bf    = qkv_bf + 12l * 1024 * 1024;
    __hip_bfloat16* u_bf    = o_bf + 4l * 1024 * 1024;

    cvt_kernel<<<(3 * 1024 * 1024 / 4 + 255) / 256, 256, 0, stream>>>(qkv_w, qkvw_bf, 3 * 1024 * 1024 / 4);
    cvt_kernel<<<(4 * 1024 * 1024 / 4 + 255) / 256, 256, 0, stream>>>(fc1_w, fc1w_bf, 4 * 1024 * 1024 / 4);
    cvt_kernel<<<(4 * 1024 * 1024 / 4 + 255) / 256, 256, 0, stream>>>(fc2_w, fc2w_bf, 4 * 1024 * 1024 / 4);
    cvt_kernel<<<(1024 * 1024 / 4 + 255) / 256, 256, 0, stream>>>(proj_w, projw_bf, 1024 * 1024 / 4);

    ln_f32_kernel<<<TOKENS, 256, 0, stream>>>(x, ln1_g, ln1_b, h_bf, CDIM);
    gemm_mfma<<<dim3(3072 / GBN, TOKENS / GBM), 256, 0, stream>>>(
        h_bf, qkvw_bf, nullptr, nullptr, qkv_bf, TOKENS, 3072, CDIM, 0, 1);
    attn_mfma<<<1024, 256, 0, stream>>>(qkv_bf, o_bf);
    gemm_mfma<<<dim3(CDIM / GBN, TOKENS / GBM), 256, 0, stream>>>(
        o_bf, projw_bf, proj_b, x, out, TOKENS, CDIM, CDIM, 0, 0);
    ln_f32_kernel<<<TOKENS, 256, 0, stream>>>(out, ln2_g, ln2_b, h_bf, CDIM);
    gemm_mfma<<<dim3(HID / GBN, TOKENS / GBM), 256, 0, stream>>>(
        h_bf, fc1w_bf, fc1_b, nullptr, u_bf, TOKENS, HID, CDIM, 1, 1);
    ln_bf16_kernel<<<TOKENS, 256, 0, stream>>>(u_bf, lnh_g, lnh_b, u_bf, HID);
    gemm_mfma<<<dim3(CDIM / GBN, TOKENS / GBM), 256, 0, stream>>>(
        u_bf, fc2w_bf, fc2_b, out, out, TOKENS, CDIM, HID, 0, 0);
}

// Round 4
// 458.791 us; speedup vs baseline: 6.9798x; 1.0987x over previous
//
#include <hip/hip_runtime.h>
#include <hip/hip_bf16.h>
#include <math.h>

// ---------------------------------------------------------------------------
// Transformer block. R3: GEMM K-loop restructured — double-buffered LDS with
// ONE barrier per iteration; global_load_lds for tile k+1 issued immediately
// after the barrier, so the compiler's vmcnt(0) drain at the next barrier
// waits on loads that have a full compute phase in flight (software pipeline
// the 2-barrier m97 structure can't express). N=1024 GEMMs use TN=64 tiles
// (512 blocks = 2/CU instead of 1/CU).
// Attention: MFMA flash kernel (R2). LN/cvt unchanged.
// ---------------------------------------------------------------------------

#define TOKENS 4096
#define CDIM   1024
#define HEADS  16
#define DHEAD  64
#define HID    4096

typedef __attribute__((ext_vector_type(4))) float  floatx4;
typedef __attribute__((ext_vector_type(8))) short  short8;  // 8 x bf16 frag

// ---------------- fp32 -> bf16 convert (weights) ----------------
__global__ __launch_bounds__(256) void cvt_kernel(
    const float* __restrict__ in, __hip_bfloat16* __restrict__ out, int n4)
{
    int i = blockIdx.x * 256 + threadIdx.x;
    if (i < n4) {
        float4 v = ((const float4*)in)[i];
        __hip_bfloat16 t[4];
        t[0] = __float2bfloat16(v.x);
        t[1] = __float2bfloat16(v.y);
        t[2] = __float2bfloat16(v.z);
        t[3] = __float2bfloat16(v.w);
        *(uint2*)(out + 4l * i) = *(uint2*)t;
    }
}

// ---------------- LayerNorm: fp32 in -> bf16 out ----------------
__global__ __launch_bounds__(256) void ln_f32_kernel(
    const float* __restrict__ x, const float* __restrict__ g,
    const float* __restrict__ b, __hip_bfloat16* __restrict__ y, int C)
{
    int row = blockIdx.x;
    const float* xr = x + (long)row * C;
    __hip_bfloat16* yr = y + (long)row * C;

    float s = 0.f, ss = 0.f;
    for (int i = threadIdx.x; i < C; i += 256) {
        float v = xr[i];
        s += v; ss += v * v;
    }
    #pragma unroll
    for (int d = 32; d; d >>= 1) {
        s  += __shfl_down(s, d);
        ss += __shfl_down(ss, d);
    }
    __shared__ float buf[4][2];
    int wid = threadIdx.x >> 6, lane = threadIdx.x & 63;
    if (lane == 0) { buf[wid][0] = s; buf[wid][1] = ss; }
    __syncthreads();
    if (threadIdx.x == 0) {
        s = buf[0][0] + buf[1][0] + buf[2][0] + buf[3][0];
        ss = buf[0][1] + buf[1][1] + buf[2][1] + buf[3][1];
        buf[0][0] = s; buf[0][1] = ss;
    }
    __syncthreads();
    s = buf[0][0]; ss = buf[0][1];

    float invC = 1.f / (float)C;
    float mu = s * invC;
    float var = ss * invC - mu * mu;
    float inv = rsqrtf(var + 1e-5f);
    for (int i = threadIdx.x; i < C; i += 256) {
        yr[i] = __float2bfloat16((xr[i] - mu) * inv * g[i] + b[i]);
    }
}

// ---------------- LayerNorm: bf16 in -> bf16 out (in place ok) ----------------
__global__ __launch_bounds__(256) void ln_bf16_kernel(
    const __hip_bfloat16* __restrict__ x, const float* __restrict__ g,
    const float* __restrict__ b, __hip_bfloat16* __restrict__ y, int C)
{
    int row = blockIdx.x;
    const __hip_bfloat16* xr = x + (long)row * C;
    __hip_bfloat16* yr = y + (long)row * C;

    float s = 0.f, ss = 0.f;
    for (int i = threadIdx.x; i < C; i += 256) {
        float v = __bfloat162float(xr[i]);
        s += v; ss += v * v;
    }
    #pragma unroll
    for (int d = 32; d; d >>= 1) {
        s  += __shfl_down(s, d);
        ss += __shfl_down(ss, d);
    }
    __shared__ float buf[4][2];
    int wid = threadIdx.x >> 6, lane = threadIdx.x & 63;
    if (lane == 0) { buf[wid][0] = s; buf[wid][1] = ss; }
    __syncthreads();
    if (threadIdx.x == 0) {
        s = buf[0][0] + buf[1][0] + buf[2][0] + buf[3][0];
        ss = buf[0][1] + buf[1][1] + buf[2][1] + buf[3][1];
        buf[0][0] = s; buf[0][1] = ss;
    }
    __syncthreads();
    s = buf[0][0]; ss = buf[0][1];

    float invC = 1.f / (float)C;
    float mu = s * invC;
    float var = ss * invC - mu * mu;
    float inv = rsqrtf(var + 1e-5f);
    for (int i = threadIdx.x; i < C; i += 256) {
        float v = __bfloat162float(xr[i]);
        yr[i] = __float2bfloat16((v - mu) * inv * g[i] + b[i]);
    }
}

// ---------------- async 16B global->LDS ----------------
__device__ __forceinline__ void gld_lds16(const void* gp, void* lp)
{
    __builtin_amdgcn_global_load_lds(
        (__attribute__((address_space(1))) void*)(gp),
        (__attribute__((address_space(3))) void*)(lp),
        16, 0, 0);
}

// ---------------- bf16 MFMA GEMM, pipelined double-buffer ----------------
// C = A[M,K] @ W[N,K]^T (+bias)(+gelu-erf)(+residual)
// Tile 128 x TN, BK=32, 256 threads = 4 waves.
//   TN=128: waves 2x2, wave tile 64x64 (FI=4,FJ=4)
//   TN=64 : waves 4x1, wave tile 32x64 (FI=2,FJ=4)
// K-loop: one __syncthreads per iter; stage(k+1) issued right after it.
#define GBK 32
template <int TN>
__global__ __launch_bounds__(256) void gemm_mfma(
    const __hip_bfloat16* __restrict__ A,
    const __hip_bfloat16* __restrict__ W,
    const float* __restrict__ bias, const float* __restrict__ residual,
    void* __restrict__ Cout, int M, int N, int K, int act, int out_bf16)
{
    constexpr int WN = (TN == 128) ? 2 : 1;
    constexpr int WM = 4 / WN;
    constexpr int FJ = TN / (WN * 16);      // 4
    constexpr int FI = 128 / (WM * 16);     // 4 or 2
    constexpr int ACH = 8;                  // A chunks (128*32 / 512)
    constexpr int BCH = TN / 16;            // B chunks

    __shared__ __hip_bfloat16 Asl[2][128 * GBK];
    __shared__ __hip_bfloat16 Bsl[2][TN * GBK];

    int tid = threadIdx.x;
    int wave = tid >> 6, lane = tid & 63;
    int bm = blockIdx.y * 128, bn = blockIdx.x * TN;
    int wm = wave & (WM - 1), wn = wave / WM;
    int fm = lane & 15;
    int quad = lane >> 4;

    floatx4 acc[FI][FJ] = {};

    // staging: chunk c = 16 rows x 32 bf16 (1 KB); lane -> row c*16 + lane/4,
    // byte offset lane*16 from chunk base (wave-uniform base + lane*16).
    int srow = (lane >> 2);
    int skk  = (lane & 3) * 8;

    const int nk = K / GBK;

    auto stage = [&](int kt, int buf) {
        const int k0 = kt * GBK;
        #pragma unroll
        for (int c = wave; c < ACH; c += 4)
            gld_lds16(A + (long)(bm + c * 16 + srow) * K + k0 + skk,
                      &Asl[buf][c * 512]);
        #pragma unroll
        for (int c = wave; c < BCH; c += 4)
            gld_lds16(W + (long)(bn + c * 16 + srow) * K + k0 + skk,
                      &Bsl[buf][c * 512]);
    };

    stage(0, 0);

    for (int kt = 0; kt < nk; ++kt) {
        int buf = kt & 1;
        __syncthreads();                 // drains loads for this buf
        if (kt + 1 < nk) stage(kt + 1, buf ^ 1);

        const __hip_bfloat16* Ab = Asl[buf];
        const __hip_bfloat16* Bb = Bsl[buf];
        short8 af[FI], bfr[FJ];
        #pragma unroll
        for (int i = 0; i < FI; ++i)
            af[i] = *(const short8*)(Ab + (wm * FI * 16 + i * 16 + fm) * GBK + quad * 8);
        #pragma unroll
        for (int j = 0; j < FJ; ++j)
            bfr[j] = *(const short8*)(Bb + (wn * FJ * 16 + j * 16 + fm) * GBK + quad * 8);
        #pragma unroll
        for (int i = 0; i < FI; ++i)
            #pragma unroll
            for (int j = 0; j < FJ; ++j)
                acc[i][j] = __builtin_amdgcn_mfma_f32_16x16x32_bf16(
                    af[i], bfr[j], acc[i][j], 0, 0, 0);
    }

    int mbase = bm + wm * FI * 16;
    int nbase = bn + wn * FJ * 16;
    #pragma unroll
    for (int i = 0; i < FI; ++i) {
        #pragma unroll
        for (int j = 0; j < FJ; ++j) {
            int ncol = nbase + j * 16 + fm;
            #pragma unroll
            for (int r = 0; r < 4; ++r) {
                int mrow = mbase + i * 16 + quad * 4 + r;
                float v = acc[i][j][r];
                if (bias) v += bias[ncol];
                if (act == 1) v = 0.5f * v * (1.f + erff(v * 0.70710678118654752f));
                if (residual) v += residual[(long)mrow * N + ncol];
                if (out_bf16)
                    ((__hip_bfloat16*)Cout)[(long)mrow * N + ncol] = __float2bfloat16(v);
                else
                    ((float*)Cout)[(long)mrow * N + ncol] = v;
            }
        }
    }
}

// ---------------- MFMA flash attention (R2, unchanged) ----------------
__global__ __launch_bounds__(256) void attn_mfma(
    const __hip_bfloat16* __restrict__ qkv, __hip_bfloat16* __restrict__ o_out)
{
    __shared__ __align__(16) char Ks[64 * 144];
    __shared__ __align__(16) char Vt[64 * 144];
    __shared__ __align__(16) char Ps[4 * 16 * 144];

    const int C3 = 3 * CDIM;
    int wg = blockIdx.x;
    int bh = wg >> 4, qt = wg & 15;
    int b = bh >> 4, hh = bh & 15;
    int tid = threadIdx.x, wave = tid >> 6, lane = tid & 63;
    int l = lane & 15, quad = lane >> 4;

    const __hip_bfloat16* qrow =
        qkv + (long)(b * 1024 + qt * 64 + wave * 16 + l) * C3 + hh * DHEAD;
    short8 qf0 = *(const short8*)(qrow + quad * 8);
    short8 qf1 = *(const short8*)(qrow + 32 + quad * 8);

    char* Psw = Ps + wave * (16 * 144);

    int sc = tid & 7;
    int skl = tid >> 3;

    const __hip_bfloat16* Kbase = qkv + (long)(b * 1024) * C3 + CDIM + hh * DHEAD;
    const __hip_bfloat16* Vbase = qkv + (long)(b * 1024) * C3 + 2 * CDIM + hh * DHEAD;

    floatx4 facc[4] = {};
    float mrun = -1e30f, lrun = 0.f;

    #pragma unroll 1
    for (int kt = 0; kt < 16; ++kt) {
        __syncthreads();
        {
            const __hip_bfloat16* Kg = Kbase + (long)(kt * 64) * C3;
            #pragma unroll
            for (int it = 0; it < 2; ++it) {
                int key = skl + 32 * it;
                uint4 kv = *(const uint4*)(Kg + (long)key * C3 + sc * 8);
                *(uint4*)(Ks + key * 144 + sc * 16) = kv;
            }
            const __hip_bfloat16* Vg = Vbase + (long)(kt * 64) * C3;
            uint4 v0 = *(const uint4*)(Vg + (long)(2 * skl) * C3 + sc * 8);
            uint4 v1 = *(const uint4*)(Vg + (long)(2 * skl + 1) * C3 + sc * 8);
            const ushort* e0 = (const ushort*)&v0;
            const ushort* e1 = (const ushort*)&v1;
        int kpp = skl ^ (sc << 2);
            #pragma unroll
            for (int j = 0; j < 8; ++j) {
                unsigned dw = (unsigned)e0[j] | ((unsigned)e1[j] << 16);
                int d = sc * 8 + j;
                *(unsigned*)(Vt + d * 144 + kpp * 4) = dw;
            }
        }
        __syncthreads();

        floatx4 st[4] = {};
        #pragma unroll
        for (int kb = 0; kb < 4; ++kb) {
            short8 k0 = *(const short8*)(Ks + (kb * 16 + l) * 144 + quad * 16);
            short8 k1 = *(const short8*)(Ks + (kb * 16 + l) * 144 + 64 + quad * 16);
            st[kb] = __builtin_amdgcn_mfma_f32_16x16x32_bf16(k0, qf0, st[kb], 0, 0, 0);
            st[kb] = __builtin_amdgcn_mfma_f32_16x16x32_bf16(k1, qf1, st[kb], 0, 0, 0);
        }

        float p[16];
        float tm = -1e30f;
        #pragma unroll
        for (int kb = 0; kb < 4; ++kb)
            #pragma unroll
            for (int r = 0; r < 4; ++r) {
                float s = st[kb][r] * 0.125f;
                p[kb * 4 + r] = s;
                tm = fmaxf(tm, s);
            }
        tm = fmaxf(tm, __shfl_xor(tm, 16));
        tm = fmaxf(tm, __shfl_xor(tm, 32));
        float mn = fmaxf(mrun, tm);
        float alpha = __expf(mrun - mn);
        float psum = 0.f;
        #pragma unroll
        for (int i = 0; i < 16; ++i) { p[i] = __expf(p[i] - mn); psum += p[i]; }
        psum += __shfl_xor(psum, 16);
        psum += __shfl_xor(psum, 32);
        lrun = lrun * alpha + psum;
        mrun = mn;

        #pragma unroll
        for (int kb = 0; kb < 4; ++kb) {
            __hip_bfloat16 t[4];
            #pragma unroll
            for (int r = 0; r < 4; ++r) t[r] = __float2bfloat16(p[kb * 4 + r]);
            *(uint2*)(Psw + l * 144 + kb * 32 + quad * 8) = *(const uint2*)t;
        }

        float a0 = __shfl(alpha, quad * 4 + 0);
        float a1 = __shfl(alpha, quad * 4 + 1);
        float a2 = __shfl(alpha, quad * 4 + 2);
        float a3 = __shfl(alpha, quad * 4 + 3);
        #pragma unroll
        for (int db = 0; db < 4; ++db) {
            facc[db][0] *= a0; facc[db][1] *= a1;
            facc[db][2] *= a2; facc[db][3] *= a3;
        }

        short8 pf0 = *(const short8*)(Psw + l * 144 + quad * 16);
        short8 pf1 = *(const short8*)(Psw + l * 144 + 64 + quad * 16);
        #pragma unroll
        for (int db = 0; db < 4; ++db) {
            int d = db * 16 + l;
            int o3 = (d >> 3) & 7;
            short8 v0 = *(const short8*)(Vt + d * 144 + ((quad ^ o3) << 4));
            short8 v1 = *(const short8*)(Vt + d * 144 + (((4 + quad) ^ o3) << 4));
            facc[db] = __builtin_amdgcn_mfma_f32_16x16x32_bf16(pf0, v0, facc[db], 0, 0, 0);
            facc[db] = __builtin_amdgcn_mfma_f32_16x16x32_bf16(pf1, v1, facc[db], 0, 0, 0);
        }
    }

    float il0 = 1.f / __shfl(lrun, quad * 4 + 0);
    float il1 = 1.f / __shfl(lrun, quad * 4 + 1);
    float il2 = 1.f / __shfl(lrun, quad * 4 + 2);
    float il3 = 1.f / __shfl(lrun, quad * 4 + 3);
    __hip_bfloat16* orow =
        o_out + (long)(b * 1024 + qt * 64 + wave * 16) * CDIM + hh * DHEAD;
    #pragma unroll
    for (int db = 0; db < 4; ++db) {
        int col = db * 16 + l;
        orow[(quad * 4 + 0) * CDIM + col] = __float2bfloat16(facc[db][0] * il0);
        orow[(quad * 4 + 1) * CDIM + col] = __float2bfloat16(facc[db][1] * il1);
        orow[(quad * 4 + 2) * CDIM + col] = __float2bfloat16(facc[db][2] * il2);
        orow[(quad * 4 + 3) * CDIM + col] = __float2bfloat16(facc[db][3] * il3);
    }
}

// ---------------------------------------------------------------------------
extern "C" void kernel_launch(void* const* d_in, const int* in_sizes, int n_in,
                              void* d_out, int out_size, void* d_ws, size_t ws_size,
                              hipStream_t stream)
{
    const float* x      = (const float*)d_in[0];
    const float* qkv_w  = (const float*)d_in[1];
    const float* proj_w = (const float*)d_in[2];
    const float* proj_b = (const float*)d_in[3];
    const float* fc1_w  = (const float*)d_in[4];
    const float* fc1_b  = (const float*)d_in[5];
    const float* fc2_w  = (const float*)d_in[6];
    const float* fc2_b  = (const float*)d_in[7];
    const float* ln1_g  = (const float*)d_in[8];
    const float* ln1_b  = (const float*)d_in[9];
    const float* ln2_g  = (const float*)d_in[10];
    const float* ln2_b  = (const float*)d_in[11];
    const float* lnh_g  = (const float*)d_in[12];
    const float* lnh_b  = (const float*)d_in[13];

    float* out = (float*)d_out;

    __hip_bfloat16* wsb     = (__hip_bfloat16*)d_ws;
    __hip_bfloat16* qkvw_bf = wsb;
    __hip_bfloat16* fc1w_bf = qkvw_bf + 3l * 1024 * 1024;
    __hip_bfloat16* fc2w_bf = fc1w_bf + 4l * 1024 * 1024;
    __hip_bfloat16* projw_bf= fc2w_bf + 4l * 1024 * 1024;
    __hip_bfloat16* h_bf    = projw_bf + 1l * 1024 * 1024;
    __hip_bfloat16* qkv_bf  = h_bf + 4l * 1024 * 1024;
    __hip_bfloat16* o_bf    = qkv_bf + 12l * 1024 * 1024;
    __hip_bfloat16* u_bf    = o_bf + 4l * 1024 * 1024;

    cvt_kernel<<<(3 * 1024 * 1024 / 4 + 255) / 256, 256, 0, stream>>>(qkv_w, qkvw_bf, 3 * 1024 * 1024 / 4);
    cvt_kernel<<<(4 * 1024 * 1024 / 4 + 255) / 256, 256, 0, stream>>>(fc1_w, fc1w_bf, 4 * 1024 * 1024 / 4);
    cvt_kernel<<<(4 * 1024 * 1024 / 4 + 255) / 256, 256, 0, stream>>>(fc2_w, fc2w_bf, 4 * 1024 * 1024 / 4);
    cvt_kernel<<<(1024 * 1024 / 4 + 255) / 256, 256, 0, stream>>>(proj_w, projw_bf, 1024 * 1024 / 4);

    // 1. h = LN1(x)
    ln_f32_kernel<<<TOKENS, 256, 0, stream>>>(x, ln1_g, ln1_b, h_bf, CDIM);
    // 2. qkv = h @ qkv_w^T
    gemm_mfma<128><<<dim3(3072 / 128, TOKENS / 128), 256, 0, stream>>>(
        h_bf, qkvw_bf, nullptr, nullptr, qkv_bf, TOKENS, 3072, CDIM, 0, 1);
    // 3. o = attention(qkv)
    attn_mfma<<<1024, 256, 0, stream>>>(qkv_bf, o_bf);
    // 4. out = x + o @ proj_w^T + proj_b   (TN=64: 512 blocks)
    gemm_mfma<64><<<dim3(CDIM / 64, TOKENS / 128), 256, 0, stream>>>(
        o_bf, projw_bf, proj_b, x, out, TOKENS, CDIM, CDIM, 0, 0);
    // 5. h2 = LN2(out)
    ln_f32_kernel<<<TOKENS, 256, 0, stream>>>(out, ln2_g, ln2_b, h_bf, CDIM);
    // 6. u = gelu(h2 @ fc1_w^T + fc1_b)
    gemm_mfma<128><<<dim3(HID / 128, TOKENS / 128), 256, 0, stream>>>(
        h_bf, fc1w_bf, fc1_b, nullptr, u_bf, TOKENS, HID, CDIM, 1, 1);
    // 7. u = LNh(u) in place
    ln_bf16_kernel<<<TOKENS, 256, 0, stream>>>(u_bf, lnh_g, lnh_b, u_bf, HID);
    // 8. out = out + u @ fc2_w^T + fc2_b   (TN=64: 512 blocks)
    gemm_mfma<64><<<dim3(CDIM / 64, TOKENS / 128), 256, 0, stream>>>(
        u_bf, fc2w_bf, fc2_b, out, out, TOKENS, CDIM, HID, 0, 0);
}

// Round 5
// 410.633 us; speedup vs baseline: 7.7984x; 1.1173x over previous
//
#include <hip/hip_runtime.h>
#include <hip/hip_bf16.h>
#include <math.h>

// ---------------------------------------------------------------------------
// Transformer block. R4: GEMM staging switched LDS-DMA -> global_load-to-VGPR
// + ds_write (AITER-style). Plain register loads need NO vmcnt(0) drain at
// s_barrier (the drain was R3's stall: global_load_lds forces vmcnt(0) before
// every barrier). Pipeline: compute(buf) | ds_write regs(kt+1)->buf^1 |
// gload(kt+2) | barrier(lgkm-only drain). One barrier/iter, double buffer.
// __launch_bounds__(256,3) targets 3 blocks/CU so barriers of co-resident
// blocks stagger. cvt kernels fused 4->1 (9 dispatches total).
// Attention: MFMA flash kernel (R2, unchanged).
// ---------------------------------------------------------------------------

#define TOKENS 4096
#define CDIM   1024
#define HEADS  16
#define DHEAD  64
#define HID    4096

typedef __attribute__((ext_vector_type(4))) float  floatx4;
typedef __attribute__((ext_vector_type(8))) short  short8;  // 8 x bf16 frag

// ---------------- fused fp32 -> bf16 weight convert ----------------
// dst regions contiguous in ws: qkv[3M] | fc1[4M] | fc2[4M] | proj[1M] floats.
__global__ __launch_bounds__(256) void cvt_all(
    const float* __restrict__ s0, const float* __restrict__ s1,
    const float* __restrict__ s2, const float* __restrict__ s3,
    __hip_bfloat16* __restrict__ dst)
{
    long i = (long)blockIdx.x * 256 + threadIdx.x;   // float4 index, 3M total
    const float* src;
    long base;
    if (i < 768l * 1024)       { src = s0; base = 0; }
    else if (i < 1792l * 1024) { src = s1; base = 768l * 1024; }
    else if (i < 2816l * 1024) { src = s2; base = 1792l * 1024; }
    else                       { src = s3; base = 2816l * 1024; }
    float4 v = ((const float4*)src)[i - base];
    __hip_bfloat16 t[4];
    t[0] = __float2bfloat16(v.x);
    t[1] = __float2bfloat16(v.y);
    t[2] = __float2bfloat16(v.z);
    t[3] = __float2bfloat16(v.w);
    *(uint2*)(dst + 4l * i) = *(uint2*)t;
}

// ---------------- LayerNorm: fp32 in -> bf16 out ----------------
__global__ __launch_bounds__(256) void ln_f32_kernel(
    const float* __restrict__ x, const float* __restrict__ g,
    const float* __restrict__ b, __hip_bfloat16* __restrict__ y, int C)
{
    int row = blockIdx.x;
    const float* xr = x + (long)row * C;
    __hip_bfloat16* yr = y + (long)row * C;

    float s = 0.f, ss = 0.f;
    for (int i = threadIdx.x; i < C; i += 256) {
        float v = xr[i];
        s += v; ss += v * v;
    }
    #pragma unroll
    for (int d = 32; d; d >>= 1) {
        s  += __shfl_down(s, d);
        ss += __shfl_down(ss, d);
    }
    __shared__ float buf[4][2];
    int wid = threadIdx.x >> 6, lane = threadIdx.x & 63;
    if (lane == 0) { buf[wid][0] = s; buf[wid][1] = ss; }
    __syncthreads();
    if (threadIdx.x == 0) {
        s = buf[0][0] + buf[1][0] + buf[2][0] + buf[3][0];
        ss = buf[0][1] + buf[1][1] + buf[2][1] + buf[3][1];
        buf[0][0] = s; buf[0][1] = ss;
    }
    __syncthreads();
    s = buf[0][0]; ss = buf[0][1];

    float invC = 1.f / (float)C;
    float mu = s * invC;
    float var = ss * invC - mu * mu;
    float inv = rsqrtf(var + 1e-5f);
    for (int i = threadIdx.x; i < C; i += 256) {
        yr[i] = __float2bfloat16((xr[i] - mu) * inv * g[i] + b[i]);
    }
}

// ---------------- LayerNorm: bf16 in -> bf16 out (in place ok) ----------------
__global__ __launch_bounds__(256) void ln_bf16_kernel(
    const __hip_bfloat16* __restrict__ x, const float* __restrict__ g,
    const float* __restrict__ b, __hip_bfloat16* __restrict__ y, int C)
{
    int row = blockIdx.x;
    const __hip_bfloat16* xr = x + (long)row * C;
    __hip_bfloat16* yr = y + (long)row * C;

    float s = 0.f, ss = 0.f;
    for (int i = threadIdx.x; i < C; i += 256) {
        float v = __bfloat162float(xr[i]);
        s += v; ss += v * v;
    }
    #pragma unroll
    for (int d = 32; d; d >>= 1) {
        s  += __shfl_down(s, d);
        ss += __shfl_down(ss, d);
    }
    __shared__ float buf[4][2];
    int wid = threadIdx.x >> 6, lane = threadIdx.x & 63;
    if (lane == 0) { buf[wid][0] = s; buf[wid][1] = ss; }
    __syncthreads();
    if (threadIdx.x == 0) {
        s = buf[0][0] + buf[1][0] + buf[2][0] + buf[3][0];
        ss = buf[0][1] + buf[1][1] + buf[2][1] + buf[3][1];
        buf[0][0] = s; buf[0][1] = ss;
    }
    __syncthreads();
    s = buf[0][0]; ss = buf[0][1];

    float invC = 1.f / (float)C;
    float mu = s * invC;
    float var = ss * invC - mu * mu;
    float inv = rsqrtf(var + 1e-5f);
    for (int i = threadIdx.x; i < C; i += 256) {
        float v = __bfloat162float(xr[i]);
        yr[i] = __float2bfloat16((v - mu) * inv * g[i] + b[i]);
    }
}

// ---------------- bf16 MFMA GEMM, VGPR-staged pipeline ----------------
// C = A[M,K] @ W[N,K]^T (+bias)(+gelu-erf)(+residual)
// Tile 128 x TN, BK=32, 256 threads = 4 waves.
//   TN=128: waves 2x2, wave tile 64x64 (FI=4,FJ=4), LDS 32 KB
//   TN=64 : waves 4x1, wave tile 32x64 (FI=2,FJ=4), LDS 24 KB
// Per thread staging: A rows (wave*16+srow, +64), B same (TN=128) / one (TN=64).
template <int TN>
__global__ __launch_bounds__(256, 3) void gemm_mfma(
    const __hip_bfloat16* __restrict__ A,
    const __hip_bfloat16* __restrict__ W,
    const float* __restrict__ bias, const float* __restrict__ residual,
    void* __restrict__ Cout, int M, int N, int K, int act, int out_bf16)
{
    constexpr int WN = (TN == 128) ? 2 : 1;
    constexpr int WM = 4 / WN;              // 2 or 4
    constexpr int FJ = 4;
    constexpr int FI = 128 / (WM * 16);     // 4 or 2

    __shared__ __hip_bfloat16 Asl[2][128 * 32];
    __shared__ __hip_bfloat16 Bsl[2][TN * 32];

    int tid = threadIdx.x;
    int wave = tid >> 6, lane = tid & 63;
    int bm = blockIdx.y * 128, bn = blockIdx.x * TN;
    int wm = wave & (WM - 1), wn = wave / WM;
    int fm = lane & 15, quad = lane >> 4;

    int srow = lane >> 2;          // 0..15
    int skk  = (lane & 3) * 8;     // 0,8,16,24 (bf16 elems)

    const __hip_bfloat16* Ap = A + (long)(bm + wave * 16 + srow) * K + skk;
    const __hip_bfloat16* Bp = W + (long)(bn + wave * 16 + srow) * K + skk;
    const long a64 = (long)64 * K;

    const int nk = K / 32;
    floatx4 acc[FI][FJ] = {};
    const int aoff = (wave * 16 + srow) * 32 + skk;

    // tile 0 -> regs -> buf 0
    uint4 a0 = *(const uint4*)(Ap);
    uint4 a1 = *(const uint4*)(Ap + a64);
    uint4 b0 = *(const uint4*)(Bp);
    uint4 b1 = {};
    if (TN == 128) b1 = *(const uint4*)(Bp + a64);

    *(uint4*)&Asl[0][aoff] = a0;
    *(uint4*)&Asl[0][aoff + 2048] = a1;
    *(uint4*)&Bsl[0][aoff] = b0;
    if (TN == 128) *(uint4*)&Bsl[0][aoff + 2048] = b1;

    // tile 1 -> regs
    a0 = *(const uint4*)(Ap + 32);
    a1 = *(const uint4*)(Ap + a64 + 32);
    b0 = *(const uint4*)(Bp + 32);
    if (TN == 128) b1 = *(const uint4*)(Bp + a64 + 32);

    __syncthreads();

    for (int kt = 0; kt < nk; ++kt) {
        const int buf = kt & 1;
        const __hip_bfloat16* Ab = Asl[buf];
        const __hip_bfloat16* Bb = Bsl[buf];

        short8 bfr[FJ];
        #pragma unroll
        for (int j = 0; j < FJ; ++j)
            bfr[j] = *(const short8*)(Bb + (wn * 64 + j * 16 + fm) * 32 + quad * 8);
        #pragma unroll
        for (int i = 0; i < FI; ++i) {
            short8 af = *(const short8*)(Ab + (wm * FI * 16 + i * 16 + fm) * 32 + quad * 8);
            #pragma unroll
            for (int j = 0; j < FJ; ++j)
                acc[i][j] = __builtin_amdgcn_mfma_f32_16x16x32_bf16(
                    af, bfr[j], acc[i][j], 0, 0, 0);
        }

        if (kt + 1 < nk) {
            const int nb = buf ^ 1;
            *(uint4*)&Asl[nb][aoff] = a0;            // vmcnt wait lands here,
            *(uint4*)&Asl[nb][aoff + 2048] = a1;     // one iter after issue
            *(uint4*)&Bsl[nb][aoff] = b0;
            if (TN == 128) *(uint4*)&Bsl[nb][aoff + 2048] = b1;
            if (kt + 2 < nk) {
                const long o = (long)(kt + 2) * 32;
                a0 = *(const uint4*)(Ap + o);
                a1 = *(const uint4*)(Ap + a64 + o);
                b0 = *(const uint4*)(Bp + o);
                if (TN == 128) b1 = *(const uint4*)(Bp + a64 + o);
            }
        }
        __syncthreads();   // lgkm drain only (ds_writes) — no vmcnt(0)
    }

    int mbase = bm + wm * FI * 16;
    int nbase = bn + wn * 64;
    #pragma unroll
    for (int i = 0; i < FI; ++i) {
        #pragma unroll
        for (int j = 0; j < FJ; ++j) {
            int ncol = nbase + j * 16 + fm;
            #pragma unroll
            for (int r = 0; r < 4; ++r) {
                int mrow = mbase + i * 16 + quad * 4 + r;
                float v = acc[i][j][r];
                if (bias) v += bias[ncol];
                if (act == 1) v = 0.5f * v * (1.f + erff(v * 0.70710678118654752f));
                if (residual) v += residual[(long)mrow * N + ncol];
                if (out_bf16)
                    ((__hip_bfloat16*)Cout)[(long)mrow * N + ncol] = __float2bfloat16(v);
                else
                    ((float*)Cout)[(long)mrow * N + ncol] = v;
            }
        }
    }
}

// ---------------- MFMA flash attention (R2, unchanged) ----------------
__global__ __launch_bounds__(256) void attn_mfma(
    const __hip_bfloat16* __restrict__ qkv, __hip_bfloat16* __restrict__ o_out)
{
    __shared__ __align__(16) char Ks[64 * 144];
    __shared__ __align__(16) char Vt[64 * 144];
    __shared__ __align__(16) char Ps[4 * 16 * 144];

    const int C3 = 3 * CDIM;
    int wg = blockIdx.x;
    int bh = wg >> 4, qt = wg & 15;
    int b = bh >> 4, hh = bh & 15;
    int tid = threadIdx.x, wave = tid >> 6, lane = tid & 63;
    int l = lane & 15, quad = lane >> 4;

    const __hip_bfloat16* qrow =
        qkv + (long)(b * 1024 + qt * 64 + wave * 16 + l) * C3 + hh * DHEAD;
    short8 qf0 = *(const short8*)(qrow + quad * 8);
    short8 qf1 = *(const short8*)(qrow + 32 + quad * 8);

    char* Psw = Ps + wave * (16 * 144);

    int sc = tid & 7;
    int skl = tid >> 3;

    const __hip_bfloat16* Kbase = qkv + (long)(b * 1024) * C3 + CDIM + hh * DHEAD;
    const __hip_bfloat16* Vbase = qkv + (long)(b * 1024) * C3 + 2 * CDIM + hh * DHEAD;

    floatx4 facc[4] = {};
    float mrun = -1e30f, lrun = 0.f;

    #pragma unroll 1
    for (int kt = 0; kt < 16; ++kt) {
        __syncthreads();
        {
            const __hip_bfloat16* Kg = Kbase + (long)(kt * 64) * C3;
            #pragma unroll
            for (int it = 0; it < 2; ++it) {
                int key = skl + 32 * it;
                uint4 kv = *(const uint4*)(Kg + (long)key * C3 + sc * 8);
                *(uint4*)(Ks + key * 144 + sc * 16) = kv;
            }
            const __hip_bfloat16* Vg = Vbase + (long)(kt * 64) * C3;
            uint4 v0 = *(const uint4*)(Vg + (long)(2 * skl) * C3 + sc * 8);
            uint4 v1 = *(const uint4*)(Vg + (long)(2 * skl + 1) * C3 + sc * 8);
            const ushort* e0 = (const ushort*)&v0;
            const ushort* e1 = (const ushort*)&v1;
            int kpp = skl ^ (sc << 2);
            #pragma unroll
            for (int j = 0; j < 8; ++j) {
                unsigned dw = (unsigned)e0[j] | ((unsigned)e1[j] << 16);
                int d = sc * 8 + j;
                *(unsigned*)(Vt + d * 144 + kpp * 4) = dw;
            }
        }
        __syncthreads();

        floatx4 st[4] = {};
        #pragma unroll
        for (int kb = 0; kb < 4; ++kb) {
            short8 k0 = *(const short8*)(Ks + (kb * 16 + l) * 144 + quad * 16);
            short8 k1 = *(const short8*)(Ks + (kb * 16 + l) * 144 + 64 + quad * 16);
            st[kb] = __builtin_amdgcn_mfma_f32_16x16x32_bf16(k0, qf0, st[kb], 0, 0, 0);
            st[kb] = __builtin_amdgcn_mfma_f32_16x16x32_bf16(k1, qf1, st[kb], 0, 0, 0);
        }

        float p[16];
        float tm = -1e30f;
        #pragma unroll
        for (int kb = 0; kb < 4; ++kb)
            #pragma unroll
            for (int r = 0; r < 4; ++r) {
                float s = st[kb][r] * 0.125f;
                p[kb * 4 + r] = s;
                tm = fmaxf(tm, s);
            }
        tm = fmaxf(tm, __shfl_xor(tm, 16));
        tm = fmaxf(tm, __shfl_xor(tm, 32));
        float mn = fmaxf(mrun, tm);
        float alpha = __expf(mrun - mn);
        float psum = 0.f;
        #pragma unroll
        for (int i = 0; i < 16; ++i) { p[i] = __expf(p[i] - mn); psum += p[i]; }
        psum += __shfl_xor(psum, 16);
        psum += __shfl_xor(psum, 32);
        lrun = lrun * alpha + psum;
        mrun = mn;

        #pragma unroll
        for (int kb = 0; kb < 4; ++kb) {
            __hip_bfloat16 t[4];
            #pragma unroll
            for (int r = 0; r < 4; ++r) t[r] = __float2bfloat16(p[kb * 4 + r]);
            *(uint2*)(Psw + l * 144 + kb * 32 + quad * 8) = *(const uint2*)t;
        }

        float a0 = __shfl(alpha, quad * 4 + 0);
        float a1 = __shfl(alpha, quad * 4 + 1);
        float a2 = __shfl(alpha, quad * 4 + 2);
        float a3 = __shfl(alpha, quad * 4 + 3);
        #pragma unroll
        for (int db = 0; db < 4; ++db) {
            facc[db][0] *= a0; facc[db][1] *= a1;
            facc[db][2] *= a2; facc[db][3] *= a3;
        }

        short8 pf0 = *(const short8*)(Psw + l * 144 + quad * 16);
        short8 pf1 = *(const short8*)(Psw + l * 144 + 64 + quad * 16);
        #pragma unroll
        for (int db = 0; db < 4; ++db) {
            int d = db * 16 + l;
            int o3 = (d >> 3) & 7;
            short8 v0 = *(const short8*)(Vt + d * 144 + ((quad ^ o3) << 4));
            short8 v1 = *(const short8*)(Vt + d * 144 + (((4 + quad) ^ o3) << 4));
            facc[db] = __builtin_amdgcn_mfma_f32_16x16x32_bf16(pf0, v0, facc[db], 0, 0, 0);
            facc[db] = __builtin_amdgcn_mfma_f32_16x16x32_bf16(pf1, v1, facc[db], 0, 0, 0);
        }
    }

    float il0 = 1.f / __shfl(lrun, quad * 4 + 0);
    float il1 = 1.f / __shfl(lrun, quad * 4 + 1);
    float il2 = 1.f / __shfl(lrun, quad * 4 + 2);
    float il3 = 1.f / __shfl(lrun, quad * 4 + 3);
    __hip_bfloat16* orow =
        o_out + (long)(b * 1024 + qt * 64 + wave * 16) * CDIM + hh * DHEAD;
    #pragma unroll
    for (int db = 0; db < 4; ++db) {
        int col = db * 16 + l;
        orow[(quad * 4 + 0) * CDIM + col] = __float2bfloat16(facc[db][0] * il0);
        orow[(quad * 4 + 1) * CDIM + col] = __float2bfloat16(facc[db][1] * il1);
        orow[(quad * 4 + 2) * CDIM + col] = __float2bfloat16(facc[db][2] * il2);
        orow[(quad * 4 + 3) * CDIM + col] = __float2bfloat16(facc[db][3] * il3);
    }
}

// ---------------------------------------------------------------------------
extern "C" void kernel_launch(void* const* d_in, const int* in_sizes, int n_in,
                              void* d_out, int out_size, void* d_ws, size_t ws_size,
                              hipStream_t stream)
{
    const float* x      = (const float*)d_in[0];
    const float* qkv_w  = (const float*)d_in[1];
    const float* proj_w = (const float*)d_in[2];
    const float* proj_b = (const float*)d_in[3];
    const float* fc1_w  = (const float*)d_in[4];
    const float* fc1_b  = (const float*)d_in[5];
    const float* fc2_w  = (const float*)d_in[6];
    const float* fc2_b  = (const float*)d_in[7];
    const float* ln1_g  = (const float*)d_in[8];
    const float* ln1_b  = (const float*)d_in[9];
    const float* ln2_g  = (const float*)d_in[10];
    const float* ln2_b  = (const float*)d_in[11];
    const float* lnh_g  = (const float*)d_in[12];
    const float* lnh_b  = (const float*)d_in[13];

    float* out = (float*)d_out;

    // ws: qkv_w[3M] | fc1_w[4M] | fc2_w[4M] | proj_w[1M] (contiguous for cvt_all)
    //     | h[4M] | qkv[12M] | o[4M] | u[16M]   (bf16 elements)
    __hip_bfloat16* wsb     = (__hip_bfloat16*)d_ws;
    __hip_bfloat16* qkvw_bf = wsb;
    __hip_bfloat16* fc1w_bf = qkvw_bf + 3l * 1024 * 1024;
    __hip_bfloat16* fc2w_bf = fc1w_bf + 4l * 1024 * 1024;
    __hip_bfloat16* projw_bf= fc2w_bf + 4l * 1024 * 1024;
    __hip_bfloat16* h_bf    = projw_bf + 1l * 1024 * 1024;
    __hip_bfloat16* qkv_bf  = h_bf + 4l * 1024 * 1024;
    __hip_bfloat16* o_bf    = qkv_bf + 12l * 1024 * 1024;
    __hip_bfloat16* u_bf    = o_bf + 4l * 1024 * 1024;

    // 0. all weights fp32 -> bf16 (one kernel, 12M floats)
    cvt_all<<<12288, 256, 0, stream>>>(qkv_w, fc1_w, fc2_w, proj_w, qkvw_bf);

    // 1. h = LN1(x)
    ln_f32_kernel<<<TOKENS, 256, 0, stream>>>(x, ln1_g, ln1_b, h_bf, CDIM);
    // 2. qkv = h @ qkv_w^T
    gemm_mfma<128><<<dim3(3072 / 128, TOKENS / 128), 256, 0, stream>>>(
        h_bf, qkvw_bf, nullptr, nullptr, qkv_bf, TOKENS, 3072, CDIM, 0, 1);
    // 3. o = attention(qkv)
    attn_mfma<<<1024, 256, 0, stream>>>(qkv_bf, o_bf);
    // 4. out = x + o @ proj_w^T + proj_b
    gemm_mfma<64><<<dim3(CDIM / 64, TOKENS / 128), 256, 0, stream>>>(
        o_bf, projw_bf, proj_b, x, out, TOKENS, CDIM, CDIM, 0, 0);
    // 5. h2 = LN2(out)
    ln_f32_kernel<<<TOKENS, 256, 0, stream>>>(out, ln2_g, ln2_b, h_bf, CDIM);
    // 6. u = gelu(h2 @ fc1_w^T + fc1_b)
    gemm_mfma<128><<<dim3(HID / 128, TOKENS / 128), 256, 0, stream>>>(
        h_bf, fc1w_bf, fc1_b, nullptr, u_bf, TOKENS, HID, CDIM, 1, 1);
    // 7. u = LNh(u) in place
    ln_bf16_kernel<<<TOKENS, 256, 0, stream>>>(u_bf, lnh_g, lnh_b, u_bf, HID);
    // 8. out = out + u @ fc2_w^T + fc2_b
    gemm_mfma<64><<<dim3(CDIM / 64, TOKENS / 128), 256, 0, stream>>>(
        u_bf, fc2w_bf, fc2_b, out, out, TOKENS, CDIM, HID, 0, 0);
}